// Round 7
// baseline (671.218 us; speedup 1.0000x reference)
//
#include <hip/hip_runtime.h>

#define RES 256
#define FDIM 16
#define ROWB 144   // bytes per per-thread activation row: 64 bf16 + 16B pad
                   // (144=36 words -> bank class 4*tid%32: 8-way on the single
                   //  per-iter b32/u16 read = negligible; keeps 16B alignment)

typedef __bf16 bf16x8 __attribute__((ext_vector_type(8)));

// One thread per point. MLP loops are ROLLED over the input dim i (code stays
// ~5 KB, I$-resident -- R2's 9000-instr unroll thrashed the 32 KB I$:
// VALUBusy 43%), UNROLLED over output j (accumulators statically indexed ->
// VGPRs, rule #20). The runtime-indexed activation x[i] lives in a per-thread
// LDS row (dynamic ds_read is fine there); the weight row W[i][*] is
// wave-uniform -> scalar loads. No barriers: LDS rows are thread-private.
__global__ __launch_bounds__(256, 4) void lh_fused(
    const float* __restrict__ pts, const float* __restrict__ rds,
    const float* __restrict__ G,   const float* __restrict__ F,
    const float* __restrict__ Ws1, const float* __restrict__ Ws2,
    const float* __restrict__ Wc1, const float* __restrict__ Wc2,
    const float* __restrict__ Wc3,
    float* __restrict__ sig_out, float* __restrict__ col_out, int N)
{
    __shared__ float4 act4[2304];               // 256 threads x 144 B = 36864 B
    char* const myrow = (char*)act4 + threadIdx.x * ROWB;

    const int p  = blockIdx.x * 256 + threadIdx.x;
    const int pc = p < N ? p : N - 1;

    // ---- ray dir early (latency overlaps gather+MLP) ----
    const float dx = rds[3*pc+0], dy = rds[3*pc+1], dz = rds[3*pc+2];

    // ---- gather + trilinear interp (fp32; byte-identical to the R2 pass) ----
    const float px = pts[3*pc+0], py = pts[3*pc+1], pz = pts[3*pc+2];
    const float fx0 = fminf(fmaxf(floorf(px - 0.5f), 0.f), 255.f);
    const float fy0 = fminf(fmaxf(floorf(py - 0.5f), 0.f), 255.f);
    const float fz0 = fminf(fmaxf(floorf(pz - 0.5f), 0.f), 255.f);
    const float fx1 = fminf(fmaxf(floorf(px + 0.5f), 0.f), 255.f);
    const float fy1 = fminf(fmaxf(floorf(py + 0.5f), 0.f), 255.f);
    const float fz1 = fminf(fmaxf(floorf(pz + 0.5f), 0.f), 255.f);
    const int ixs[2] = { (int)fx0, (int)fx1 };
    const int iys[2] = { (int)fy0, (int)fy1 };
    const int izs[2] = { (int)fz0, (int)fz1 };
    const float ox = px - fx0, oy = py - fy0, oz = pz - fz0;
    const float wxs[2] = { 1.f - ox, ox };
    const float wys[2] = { 1.f - oy, oy };
    const float wzs[2] = { 1.f - oz, oz };

    float fv[FDIM];
    #pragma unroll
    for (int d = 0; d < FDIM; ++d) fv[d] = 0.f;
    #pragma unroll
    for (int k = 0; k < 8; ++k) {
        const int bx = (k >> 2) & 1, by = (k >> 1) & 1, bz = k & 1;
        float gv = G[(ixs[bx] * RES + iys[by]) * RES + izs[bz]];
        gv = fminf(fmaxf(gv, -1.f), 1.f);
        const float Fi  = (gv + 1.f) * 32768.f;
        const float Fif = fminf(floorf(Fi), 65535.f);
        const float Fic = fminf(ceilf(Fi),  65535.f);
        const float wfl = Fic - Fi, wcl = Fi - Fif;   // from CLIPPED idx (ref)
        const float wk = wxs[bx] * wys[by] * wzs[bz];
        const float4* rf = (const float4*)(F + (int)Fif * FDIM);
        const float4* rc = (const float4*)(F + (int)Fic * FDIM);
        #pragma unroll
        for (int q = 0; q < 4; ++q) {
            const float4 a = rf[q];
            const float4 b = rc[q];
            fv[4*q+0] = fmaf(wk, fmaf(wfl, a.x, wcl * b.x), fv[4*q+0]);
            fv[4*q+1] = fmaf(wk, fmaf(wfl, a.y, wcl * b.y), fv[4*q+1]);
            fv[4*q+2] = fmaf(wk, fmaf(wfl, a.z, wcl * b.z), fv[4*q+2]);
            fv[4*q+3] = fmaf(wk, fmaf(wfl, a.w, wcl * b.w), fv[4*q+3]);
        }
    }

    // ---- stage fv (bf16) into cols 0..15 of this thread's LDS row ----
    {
        bf16x8 v0, v1;
        #pragma unroll
        for (int i = 0; i < 8; ++i) { v0[i] = (__bf16)fv[i]; v1[i] = (__bf16)fv[8+i]; }
        *(bf16x8*)(myrow +  0) = v0;
        *(bf16x8*)(myrow + 16) = v1;
    }

    // ---- L1: h = relu(fv @ Ws1[16][64]) ; store h (bf16) to cols 0..63 ----
    {
        float h[64];
        #pragma unroll
        for (int j = 0; j < 64; ++j) h[j] = 0.f;
        #pragma unroll 1
        for (int i = 0; i < 16; ++i) {
            const float x = (float)*(const __bf16*)(myrow + 2*i);
            const float* __restrict__ w = Ws1 + i * 64;
            #pragma unroll
            for (int j = 0; j < 64; ++j) h[j] = fmaf(x, w[j], h[j]);
        }
        #pragma unroll
        for (int jq = 0; jq < 8; ++jq) {
            bf16x8 v;
            #pragma unroll
            for (int e = 0; e < 8; ++e) v[e] = (__bf16)fmaxf(h[jq*8+e], 0.f);
            *(bf16x8*)(myrow + jq*16) = v;
        }
    }

    // ---- L2: fv2 = h @ Ws2[64][16] ; sigma = fv2[0] ----
    float fv2[16];
    {
        #pragma unroll
        for (int j = 0; j < 16; ++j) fv2[j] = 0.f;
        #pragma unroll 1
        for (int i = 0; i < 64; ++i) {
            const float x = (float)*(const __bf16*)(myrow + 2*i);
            const float* __restrict__ w = Ws2 + i * 16;
            #pragma unroll
            for (int j = 0; j < 16; ++j) fv2[j] = fmaf(x, w[j], fv2[j]);
        }
    }
    if (p < N) sig_out[p] = fv2[0];

    // ---- SH deg-4 -> cols 0..15 ; fv2[1..15] -> cols 16..30 ----
    {
        const float x2 = dx*dx, y2 = dy*dy, z2 = dz*dz;
        float c[16];
        c[0]  = 0.28209479177387814f;
        c[1]  = -0.48860251190291987f * dy;
        c[2]  =  0.48860251190291987f * dz;
        c[3]  = -0.48860251190291987f * dx;
        c[4]  =  1.0925484305920792f * dx * dy;
        c[5]  = -1.0925484305920792f * dy * dz;
        c[6]  =  0.94617469575756f * z2 - 0.31539156525252005f;
        c[7]  = -1.0925484305920792f * dx * dz;
        c[8]  =  0.5462742152960396f * (x2 - y2);
        c[9]  =  0.5900435899266435f * dy * (-3.0f * x2 + y2);
        c[10] =  2.890611442640554f * dx * dy * dz;
        c[11] =  0.4570457994644657f * dy * (1.0f - 5.0f * z2);
        c[12] =  0.3731763325901154f * dz * (5.0f * z2 - 3.0f);
        c[13] =  0.4570457994644657f * dx * (1.0f - 5.0f * z2);
        c[14] =  1.445305721320277f * dz * (x2 - y2);
        c[15] =  0.5900435899266435f * dx * (-x2 + 3.0f * y2);
        bf16x8 s0, s1;
        #pragma unroll
        for (int i = 0; i < 8; ++i) { s0[i] = (__bf16)c[i]; s1[i] = (__bf16)c[8+i]; }
        *(bf16x8*)(myrow +  0) = s0;
        *(bf16x8*)(myrow + 16) = s1;
        #pragma unroll
        for (int d = 1; d < 16; ++d)
            *(__bf16*)(myrow + (15 + d) * 2) = (__bf16)fv2[d];
    }

    // ---- L3: c1 = relu(cin[31] @ Wc1[31][64]) -> cols 0..63 ----
    {
        float c1[64];
        #pragma unroll
        for (int j = 0; j < 64; ++j) c1[j] = 0.f;
        #pragma unroll 1
        for (int i = 0; i < 31; ++i) {
            const float x = (float)*(const __bf16*)(myrow + 2*i);
            const float* __restrict__ w = Wc1 + i * 64;
            #pragma unroll
            for (int j = 0; j < 64; ++j) c1[j] = fmaf(x, w[j], c1[j]);
        }
        #pragma unroll
        for (int jq = 0; jq < 8; ++jq) {
            bf16x8 v;
            #pragma unroll
            for (int e = 0; e < 8; ++e) v[e] = (__bf16)fmaxf(c1[jq*8+e], 0.f);
            *(bf16x8*)(myrow + jq*16) = v;
        }
    }

    // ---- L4: c2 = relu(c1 @ Wc2[64][64]) -> cols 0..63 ----
    {
        float c2[64];
        #pragma unroll
        for (int j = 0; j < 64; ++j) c2[j] = 0.f;
        #pragma unroll 1
        for (int i = 0; i < 64; ++i) {
            const float x = (float)*(const __bf16*)(myrow + 2*i);
            const float* __restrict__ w = Wc2 + i * 64;
            #pragma unroll
            for (int j = 0; j < 64; ++j) c2[j] = fmaf(x, w[j], c2[j]);
        }
        #pragma unroll
        for (int jq = 0; jq < 8; ++jq) {
            bf16x8 v;
            #pragma unroll
            for (int e = 0; e < 8; ++e) v[e] = (__bf16)fmaxf(c2[jq*8+e], 0.f);
            *(bf16x8*)(myrow + jq*16) = v;
        }
    }

    // ---- L5: colors = c2 @ Wc3[64][3] ----
    {
        float col0 = 0.f, col1 = 0.f, col2 = 0.f;
        #pragma unroll 1
        for (int i = 0; i < 64; ++i) {
            const float x = (float)*(const __bf16*)(myrow + 2*i);
            const float* __restrict__ w = Wc3 + i * 3;
            col0 = fmaf(x, w[0], col0);
            col1 = fmaf(x, w[1], col1);
            col2 = fmaf(x, w[2], col2);
        }
        if (p < N) {
            col_out[3*p+0] = col0;
            col_out[3*p+1] = col1;
            col_out[3*p+2] = col2;
        }
    }
}

extern "C" void kernel_launch(void* const* d_in, const int* in_sizes, int n_in,
                              void* d_out, int out_size, void* d_ws, size_t ws_size,
                              hipStream_t stream) {
    const float* pts = (const float*)d_in[0];
    const float* rds = (const float*)d_in[1];
    const float* G   = (const float*)d_in[2];
    const float* F   = (const float*)d_in[3];
    const float* Ws1 = (const float*)d_in[4];
    const float* Ws2 = (const float*)d_in[5];
    const float* Wc1 = (const float*)d_in[6];
    const float* Wc2 = (const float*)d_in[7];
    const float* Wc3 = (const float*)d_in[8];

    const int N = in_sizes[0] / 3;
    float* sig = (float*)d_out;
    float* col = (float*)d_out + N;

    const int grid = (N + 255) / 256;
    lh_fused<<<grid, 256, 0, stream>>>(pts, rds, G, F, Ws1, Ws2, Wc1, Wc2, Wc3,
                                       sig, col, N);
}

// Round 11
// 415.150 us; speedup vs baseline: 1.6168x; 1.6168x over previous
//
#include <hip/hip_runtime.h>

#define RES 256
#define FDIM 16
#define ROWB 144   // per-thread LDS row: 64 bf16 (128 B) + 16 B pad, 16B-aligned

typedef __bf16 bf16x8 __attribute__((ext_vector_type(8)));

// One thread per point. Anti-spill structure (R7 post-mortem: VGPR=64 forced
// 211 MB scratch writes): every layer computes 16-wide output chunks
// (a[16] statically-indexed accumulators, ~60 reg live set), outer loops
// ROLLED. 64-wide activations (h, c1) live in a per-thread LDS row, read as
// b128 octets with static extraction. Weights are wave-uniform -> s_load.
// L5 fused into L4 chunks (c2 never materialized). Code ~10 KB, I$-resident.
__global__ __launch_bounds__(256, 4) void lh_fused(
    const float* __restrict__ pts, const float* __restrict__ rds,
    const float* __restrict__ G,   const float* __restrict__ F,
    const float* __restrict__ Ws1, const float* __restrict__ Ws2,
    const float* __restrict__ Wc1, const float* __restrict__ Wc2,
    const float* __restrict__ Wc3,
    float* __restrict__ sig_out, float* __restrict__ col_out, int N)
{
    __shared__ float4 act4[2304];               // 256 threads x 144 B = 36864 B
    char* const myrow = (char*)act4 + threadIdx.x * ROWB;

    const int p  = blockIdx.x * 256 + threadIdx.x;
    const int pc = p < N ? p : N - 1;

    const float dx = rds[3*pc+0], dy = rds[3*pc+1], dz = rds[3*pc+2];

    // ---- gather + trilinear interp (fp32; proven in R2/R7) ----
    const float px = pts[3*pc+0], py = pts[3*pc+1], pz = pts[3*pc+2];
    const float fx0 = fminf(fmaxf(floorf(px - 0.5f), 0.f), 255.f);
    const float fy0 = fminf(fmaxf(floorf(py - 0.5f), 0.f), 255.f);
    const float fz0 = fminf(fmaxf(floorf(pz - 0.5f), 0.f), 255.f);
    const float fx1 = fminf(fmaxf(floorf(px + 0.5f), 0.f), 255.f);
    const float fy1 = fminf(fmaxf(floorf(py + 0.5f), 0.f), 255.f);
    const float fz1 = fminf(fmaxf(floorf(pz + 0.5f), 0.f), 255.f);
    const int ixs[2] = { (int)fx0, (int)fx1 };
    const int iys[2] = { (int)fy0, (int)fy1 };
    const int izs[2] = { (int)fz0, (int)fz1 };
    const float ox = px - fx0, oy = py - fy0, oz = pz - fz0;
    const float wxs[2] = { 1.f - ox, ox };
    const float wys[2] = { 1.f - oy, oy };
    const float wzs[2] = { 1.f - oz, oz };

    float fv[FDIM];
    #pragma unroll
    for (int d = 0; d < FDIM; ++d) fv[d] = 0.f;
    #pragma unroll
    for (int k = 0; k < 8; ++k) {
        const int bx = (k >> 2) & 1, by = (k >> 1) & 1, bz = k & 1;
        float gv = G[(ixs[bx] * RES + iys[by]) * RES + izs[bz]];
        gv = fminf(fmaxf(gv, -1.f), 1.f);
        const float Fi  = (gv + 1.f) * 32768.f;
        const float Fif = fminf(floorf(Fi), 65535.f);
        const float Fic = fminf(ceilf(Fi),  65535.f);
        const float wfl = Fic - Fi, wcl = Fi - Fif;   // from CLIPPED idx (ref)
        const float wk = wxs[bx] * wys[by] * wzs[bz];
        const float4* rf = (const float4*)(F + (int)Fif * FDIM);
        const float4* rc = (const float4*)(F + (int)Fic * FDIM);
        #pragma unroll
        for (int q = 0; q < 4; ++q) {
            const float4 a = rf[q];
            const float4 b = rc[q];
            fv[4*q+0] = fmaf(wk, fmaf(wfl, a.x, wcl * b.x), fv[4*q+0]);
            fv[4*q+1] = fmaf(wk, fmaf(wfl, a.y, wcl * b.y), fv[4*q+1]);
            fv[4*q+2] = fmaf(wk, fmaf(wfl, a.z, wcl * b.z), fv[4*q+2]);
            fv[4*q+3] = fmaf(wk, fmaf(wfl, a.w, wcl * b.w), fv[4*q+3]);
        }
    }

    // ---- L1: h = relu(fv @ Ws1[16][64]) in 16-wide chunks -> LDS row ----
    #pragma unroll 1
    for (int jc = 0; jc < 4; ++jc) {
        float a[16];
        #pragma unroll
        for (int j = 0; j < 16; ++j) a[j] = 0.f;
        #pragma unroll
        for (int i = 0; i < 16; ++i) {
            const float x = fv[i];
            const float* __restrict__ w = Ws1 + i * 64 + jc * 16;  // uniform
            #pragma unroll
            for (int j = 0; j < 16; ++j) a[j] = fmaf(x, w[j], a[j]);
        }
        bf16x8 p0, p1;
        #pragma unroll
        for (int e = 0; e < 8; ++e) {
            p0[e] = (__bf16)fmaxf(a[e],     0.f);
            p1[e] = (__bf16)fmaxf(a[8 + e], 0.f);
        }
        *(bf16x8*)(myrow + jc * 32)      = p0;
        *(bf16x8*)(myrow + jc * 32 + 16) = p1;
    }

    // ---- L2: fv2 = h @ Ws2[64][16] ; h read as b128 octets, static extract ----
    float fv2[16];
    #pragma unroll
    for (int j = 0; j < 16; ++j) fv2[j] = 0.f;
    #pragma unroll 1
    for (int o = 0; o < 8; ++o) {
        const bf16x8 xo = *(const bf16x8*)(myrow + o * 16);
        #pragma unroll
        for (int e = 0; e < 8; ++e) {
            const float x = (float)xo[e];
            const float* __restrict__ w = Ws2 + (o * 8 + e) * 16;  // uniform
            #pragma unroll
            for (int j = 0; j < 16; ++j) fv2[j] = fmaf(x, w[j], fv2[j]);
        }
    }
    if (p < N) sig_out[p] = fv2[0];

    // ---- SH deg-4 (fp32) + fv2[1..15] -> cin[31] in registers ----
    float cin[31];
    {
        const float x2 = dx*dx, y2 = dy*dy, z2 = dz*dz;
        cin[0]  = 0.28209479177387814f;
        cin[1]  = -0.48860251190291987f * dy;
        cin[2]  =  0.48860251190291987f * dz;
        cin[3]  = -0.48860251190291987f * dx;
        cin[4]  =  1.0925484305920792f * dx * dy;
        cin[5]  = -1.0925484305920792f * dy * dz;
        cin[6]  =  0.94617469575756f * z2 - 0.31539156525252005f;
        cin[7]  = -1.0925484305920792f * dx * dz;
        cin[8]  =  0.5462742152960396f * (x2 - y2);
        cin[9]  =  0.5900435899266435f * dy * (-3.0f * x2 + y2);
        cin[10] =  2.890611442640554f * dx * dy * dz;
        cin[11] =  0.4570457994644657f * dy * (1.0f - 5.0f * z2);
        cin[12] =  0.3731763325901154f * dz * (5.0f * z2 - 3.0f);
        cin[13] =  0.4570457994644657f * dx * (1.0f - 5.0f * z2);
        cin[14] =  1.445305721320277f * dz * (x2 - y2);
        cin[15] =  0.5900435899266435f * dx * (-x2 + 3.0f * y2);
        #pragma unroll
        for (int d = 1; d < 16; ++d) cin[15 + d] = fv2[d];
    }

    // ---- L3: c1 = relu(cin @ Wc1[31][64]) in chunks -> LDS row (reuse) ----
    #pragma unroll 1
    for (int jc = 0; jc < 4; ++jc) {
        float a[16];
        #pragma unroll
        for (int j = 0; j < 16; ++j) a[j] = 0.f;
        #pragma unroll
        for (int i = 0; i < 31; ++i) {
            const float x = cin[i];
            const float* __restrict__ w = Wc1 + i * 64 + jc * 16;  // uniform
            #pragma unroll
            for (int j = 0; j < 16; ++j) a[j] = fmaf(x, w[j], a[j]);
        }
        bf16x8 p0, p1;
        #pragma unroll
        for (int e = 0; e < 8; ++e) {
            p0[e] = (__bf16)fmaxf(a[e],     0.f);
            p1[e] = (__bf16)fmaxf(a[8 + e], 0.f);
        }
        *(bf16x8*)(myrow + jc * 32)      = p0;
        *(bf16x8*)(myrow + jc * 32 + 16) = p1;
    }

    // ---- L4+L5 fused: per 16-chunk of c2, accumulate colors immediately ----
    float c0 = 0.f, c1o = 0.f, c2o = 0.f;
    #pragma unroll 1
    for (int jc = 0; jc < 4; ++jc) {
        float a[16];
        #pragma unroll
        for (int j = 0; j < 16; ++j) a[j] = 0.f;
        #pragma unroll 1
        for (int o = 0; o < 8; ++o) {
            const bf16x8 xo = *(const bf16x8*)(myrow + o * 16);
            #pragma unroll
            for (int e = 0; e < 8; ++e) {
                const float x = (float)xo[e];
                const float* __restrict__ w = Wc2 + (o * 8 + e) * 64 + jc * 16;
                #pragma unroll
                for (int j = 0; j < 16; ++j) a[j] = fmaf(x, w[j], a[j]);
            }
        }
        #pragma unroll
        for (int j = 0; j < 16; ++j) {
            const float v = fmaxf(a[j], 0.f);
            const float* __restrict__ w3 = Wc3 + (jc * 16 + j) * 3;  // uniform
            c0  = fmaf(v, w3[0], c0);
            c1o = fmaf(v, w3[1], c1o);
            c2o = fmaf(v, w3[2], c2o);
        }
    }
    if (p < N) {
        col_out[3*p+0] = c0;
        col_out[3*p+1] = c1o;
        col_out[3*p+2] = c2o;
    }
}

extern "C" void kernel_launch(void* const* d_in, const int* in_sizes, int n_in,
                              void* d_out, int out_size, void* d_ws, size_t ws_size,
                              hipStream_t stream) {
    const float* pts = (const float*)d_in[0];
    const float* rds = (const float*)d_in[1];
    const float* G   = (const float*)d_in[2];
    const float* F   = (const float*)d_in[3];
    const float* Ws1 = (const float*)d_in[4];
    const float* Ws2 = (const float*)d_in[5];
    const float* Wc1 = (const float*)d_in[6];
    const float* Wc2 = (const float*)d_in[7];
    const float* Wc3 = (const float*)d_in[8];

    const int N = in_sizes[0] / 3;
    float* sig = (float*)d_out;
    float* col = (float*)d_out + N;

    const int grid = (N + 255) / 256;
    lh_fused<<<grid, 256, 0, stream>>>(pts, rds, G, F, Ws1, Ws2, Wc1, Wc2, Wc3,
                                       sig, col, N);
}

// Round 12
// 414.099 us; speedup vs baseline: 1.6209x; 1.0025x over previous
//
#include <hip/hip_runtime.h>

#define RES 256
#define FDIM 16
#define ROWB 144   // per-thread LDS row: 64 bf16 (128 B) + 16 B pad, 16B-aligned

typedef __bf16 bf16x8 __attribute__((ext_vector_type(8)));

// One thread per point, 16-wide accumulator chunks (anti-spill, proven R11:
// 594->326 us). R11 residue: compiler still chose VGPR=64 (targeting 8
// waves/SIMD) and spilled ~42 MB -- but LDS (36.9 KB/block) caps occupancy at
// 4 waves/SIMD regardless, so that occupancy is unusable. waves_per_eu(4,4)
// clamps the regalloc target to match the LDS cap: up to 128 VGPRs, no spill.
__global__ __launch_bounds__(256)
__attribute__((amdgpu_waves_per_eu(4, 4)))
void lh_fused(
    const float* __restrict__ pts, const float* __restrict__ rds,
    const float* __restrict__ G,   const float* __restrict__ F,
    const float* __restrict__ Ws1, const float* __restrict__ Ws2,
    const float* __restrict__ Wc1, const float* __restrict__ Wc2,
    const float* __restrict__ Wc3,
    float* __restrict__ sig_out, float* __restrict__ col_out, int N)
{
    __shared__ float4 act4[2304];               // 256 threads x 144 B = 36864 B
    char* const myrow = (char*)act4 + threadIdx.x * ROWB;

    const int p  = blockIdx.x * 256 + threadIdx.x;
    const int pc = p < N ? p : N - 1;

    const float dx = rds[3*pc+0], dy = rds[3*pc+1], dz = rds[3*pc+2];

    // ---- gather + trilinear interp (fp32; proven R2/R7/R11) ----
    const float px = pts[3*pc+0], py = pts[3*pc+1], pz = pts[3*pc+2];
    const float fx0 = fminf(fmaxf(floorf(px - 0.5f), 0.f), 255.f);
    const float fy0 = fminf(fmaxf(floorf(py - 0.5f), 0.f), 255.f);
    const float fz0 = fminf(fmaxf(floorf(pz - 0.5f), 0.f), 255.f);
    const float fx1 = fminf(fmaxf(floorf(px + 0.5f), 0.f), 255.f);
    const float fy1 = fminf(fmaxf(floorf(py + 0.5f), 0.f), 255.f);
    const float fz1 = fminf(fmaxf(floorf(pz + 0.5f), 0.f), 255.f);
    const int ixs[2] = { (int)fx0, (int)fx1 };
    const int iys[2] = { (int)fy0, (int)fy1 };
    const int izs[2] = { (int)fz0, (int)fz1 };
    const float ox = px - fx0, oy = py - fy0, oz = pz - fz0;
    const float wxs[2] = { 1.f - ox, ox };
    const float wys[2] = { 1.f - oy, oy };
    const float wzs[2] = { 1.f - oz, oz };

    float fv[FDIM];
    #pragma unroll
    for (int d = 0; d < FDIM; ++d) fv[d] = 0.f;
    #pragma unroll
    for (int k = 0; k < 8; ++k) {
        const int bx = (k >> 2) & 1, by = (k >> 1) & 1, bz = k & 1;
        float gv = G[(ixs[bx] * RES + iys[by]) * RES + izs[bz]];
        gv = fminf(fmaxf(gv, -1.f), 1.f);
        const float Fi  = (gv + 1.f) * 32768.f;
        const float Fif = fminf(floorf(Fi), 65535.f);
        const float Fic = fminf(ceilf(Fi),  65535.f);
        const float wfl = Fic - Fi, wcl = Fi - Fif;   // from CLIPPED idx (ref)
        const float wk = wxs[bx] * wys[by] * wzs[bz];
        const float4* rf = (const float4*)(F + (int)Fif * FDIM);
        const float4* rc = (const float4*)(F + (int)Fic * FDIM);
        #pragma unroll
        for (int q = 0; q < 4; ++q) {
            const float4 a = rf[q];
            const float4 b = rc[q];
            fv[4*q+0] = fmaf(wk, fmaf(wfl, a.x, wcl * b.x), fv[4*q+0]);
            fv[4*q+1] = fmaf(wk, fmaf(wfl, a.y, wcl * b.y), fv[4*q+1]);
            fv[4*q+2] = fmaf(wk, fmaf(wfl, a.z, wcl * b.z), fv[4*q+2]);
            fv[4*q+3] = fmaf(wk, fmaf(wfl, a.w, wcl * b.w), fv[4*q+3]);
        }
    }

    // ---- L1: h = relu(fv @ Ws1[16][64]) in 16-wide chunks -> LDS row ----
    #pragma unroll 1
    for (int jc = 0; jc < 4; ++jc) {
        float a[16];
        #pragma unroll
        for (int j = 0; j < 16; ++j) a[j] = 0.f;
        #pragma unroll
        for (int i = 0; i < 16; ++i) {
            const float x = fv[i];
            const float* __restrict__ w = Ws1 + i * 64 + jc * 16;  // uniform
            #pragma unroll
            for (int j = 0; j < 16; ++j) a[j] = fmaf(x, w[j], a[j]);
        }
        bf16x8 p0, p1;
        #pragma unroll
        for (int e = 0; e < 8; ++e) {
            p0[e] = (__bf16)fmaxf(a[e],     0.f);
            p1[e] = (__bf16)fmaxf(a[8 + e], 0.f);
        }
        *(bf16x8*)(myrow + jc * 32)      = p0;
        *(bf16x8*)(myrow + jc * 32 + 16) = p1;
    }

    // ---- L2: fv2 = h @ Ws2[64][16] ; h read as b128 octets, static extract ----
    float fv2[16];
    #pragma unroll
    for (int j = 0; j < 16; ++j) fv2[j] = 0.f;
    #pragma unroll 1
    for (int o = 0; o < 8; ++o) {
        const bf16x8 xo = *(const bf16x8*)(myrow + o * 16);
        #pragma unroll
        for (int e = 0; e < 8; ++e) {
            const float x = (float)xo[e];
            const float* __restrict__ w = Ws2 + (o * 8 + e) * 16;  // uniform
            #pragma unroll
            for (int j = 0; j < 16; ++j) fv2[j] = fmaf(x, w[j], fv2[j]);
        }
    }
    if (p < N) sig_out[p] = fv2[0];

    // ---- SH deg-4 (fp32) + fv2[1..15] -> cin[31] in registers ----
    float cin[31];
    {
        const float x2 = dx*dx, y2 = dy*dy, z2 = dz*dz;
        cin[0]  = 0.28209479177387814f;
        cin[1]  = -0.48860251190291987f * dy;
        cin[2]  =  0.48860251190291987f * dz;
        cin[3]  = -0.48860251190291987f * dx;
        cin[4]  =  1.0925484305920792f * dx * dy;
        cin[5]  = -1.0925484305920792f * dy * dz;
        cin[6]  =  0.94617469575756f * z2 - 0.31539156525252005f;
        cin[7]  = -1.0925484305920792f * dx * dz;
        cin[8]  =  0.5462742152960396f * (x2 - y2);
        cin[9]  =  0.5900435899266435f * dy * (-3.0f * x2 + y2);
        cin[10] =  2.890611442640554f * dx * dy * dz;
        cin[11] =  0.4570457994644657f * dy * (1.0f - 5.0f * z2);
        cin[12] =  0.3731763325901154f * dz * (5.0f * z2 - 3.0f);
        cin[13] =  0.4570457994644657f * dx * (1.0f - 5.0f * z2);
        cin[14] =  1.445305721320277f * dz * (x2 - y2);
        cin[15] =  0.5900435899266435f * dx * (-x2 + 3.0f * y2);
        #pragma unroll
        for (int d = 1; d < 16; ++d) cin[15 + d] = fv2[d];
    }

    // ---- L3: c1 = relu(cin @ Wc1[31][64]) in chunks -> LDS row (reuse) ----
    #pragma unroll 1
    for (int jc = 0; jc < 4; ++jc) {
        float a[16];
        #pragma unroll
        for (int j = 0; j < 16; ++j) a[j] = 0.f;
        #pragma unroll
        for (int i = 0; i < 31; ++i) {
            const float x = cin[i];
            const float* __restrict__ w = Wc1 + i * 64 + jc * 16;  // uniform
            #pragma unroll
            for (int j = 0; j < 16; ++j) a[j] = fmaf(x, w[j], a[j]);
        }
        bf16x8 p0, p1;
        #pragma unroll
        for (int e = 0; e < 8; ++e) {
            p0[e] = (__bf16)fmaxf(a[e],     0.f);
            p1[e] = (__bf16)fmaxf(a[8 + e], 0.f);
        }
        *(bf16x8*)(myrow + jc * 32)      = p0;
        *(bf16x8*)(myrow + jc * 32 + 16) = p1;
    }

    // ---- L4+L5 fused: per 16-chunk of c2, accumulate colors immediately ----
    float c0 = 0.f, c1o = 0.f, c2o = 0.f;
    #pragma unroll 1
    for (int jc = 0; jc < 4; ++jc) {
        float a[16];
        #pragma unroll
        for (int j = 0; j < 16; ++j) a[j] = 0.f;
        #pragma unroll 1
        for (int o = 0; o < 8; ++o) {
            const bf16x8 xo = *(const bf16x8*)(myrow + o * 16);
            #pragma unroll
            for (int e = 0; e < 8; ++e) {
                const float x = (float)xo[e];
                const float* __restrict__ w = Wc2 + (o * 8 + e) * 64 + jc * 16;
                #pragma unroll
                for (int j = 0; j < 16; ++j) a[j] = fmaf(x, w[j], a[j]);
            }
        }
        #pragma unroll
        for (int j = 0; j < 16; ++j) {
            const float v = fmaxf(a[j], 0.f);
            const float* __restrict__ w3 = Wc3 + (jc * 16 + j) * 3;  // uniform
            c0  = fmaf(v, w3[0], c0);
            c1o = fmaf(v, w3[1], c1o);
            c2o = fmaf(v, w3[2], c2o);
        }
    }
    if (p < N) {
        col_out[3*p+0] = c0;
        col_out[3*p+1] = c1o;
        col_out[3*p+2] = c2o;
    }
}

extern "C" void kernel_launch(void* const* d_in, const int* in_sizes, int n_in,
                              void* d_out, int out_size, void* d_ws, size_t ws_size,
                              hipStream_t stream) {
    const float* pts = (const float*)d_in[0];
    const float* rds = (const float*)d_in[1];
    const float* G   = (const float*)d_in[2];
    const float* F   = (const float*)d_in[3];
    const float* Ws1 = (const float*)d_in[4];
    const float* Ws2 = (const float*)d_in[5];
    const float* Wc1 = (const float*)d_in[6];
    const float* Wc2 = (const float*)d_in[7];
    const float* Wc3 = (const float*)d_in[8];

    const int N = in_sizes[0] / 3;
    float* sig = (float*)d_out;
    float* col = (float*)d_out + N;

    const int grid = (N + 255) / 256;
    lh_fused<<<grid, 256, 0, stream>>>(pts, rds, G, F, Ws1, Ws2, Wc1, Wc2, Wc3,
                                       sig, col, N);
}